// Round 2
// baseline (526.259 us; speedup 1.0000x reference)
//
#include <hip/hip_runtime.h>

typedef short short8 __attribute__((ext_vector_type(8)));
typedef float f32x4 __attribute__((ext_vector_type(4)));

#define NV 131072
#define KK 27
#define CH 64

__device__ inline unsigned short f2b(float f) {
    unsigned u = __float_as_uint(f);
    u += 0x7fffu + ((u >> 16) & 1u);   // round-to-nearest-even
    return (unsigned short)(u >> 16);
}

// feat f32 [N,C] -> bf16 bits [N,C]
__global__ void prep_feat(const float* __restrict__ feat, unsigned short* __restrict__ featb) {
    int i = blockIdx.x * blockDim.x + threadIdx.x;       // over N*C/4
    float4 v = reinterpret_cast<const float4*>(feat)[i];
    ushort4 o;
    o.x = f2b(v.x); o.y = f2b(v.y); o.z = f2b(v.z); o.w = f2b(v.w);
    reinterpret_cast<ushort4*>(featb)[i] = o;
}

// W [K][Ci][Co] f32 -> Wt [K][Co][Ci] bf16 (both layers in one launch)
__global__ void prep_w(const float* __restrict__ W1, const float* __restrict__ W2,
                       unsigned short* __restrict__ wt1, unsigned short* __restrict__ wt2) {
    int id = blockIdx.x * blockDim.x + threadIdx.x;      // 2*K*C*C
    const float* W = W1; unsigned short* wt = wt1;
    int e = id;
    if (e >= KK * CH * CH) { e -= KK * CH * CH; W = W2; wt = wt2; }
    int k = e >> 12, o = (e >> 6) & 63, c = e & 63;
    wt[e] = f2b(W[k * CH * CH + c * CH + o]);
}

// One sparse-conv layer. EPI 0: relu -> bf16 out. EPI 1: +resid, relu -> f32 out.
// Block = 256 threads = 4 waves; each wave owns 16 rows x 64 cols -> block = 64 rows.
// Grid = N/64 = 2048 blocks for high occupancy (latency-bound gather).
template <int EPI>
__global__ __launch_bounds__(256, 4) void conv_layer(
    const unsigned short* __restrict__ xb,   // [N,C] bf16 input
    const unsigned short* __restrict__ wt,   // [K,Co,Ci] bf16 transposed weights
    const float* __restrict__ bias,          // [C]
    const int* __restrict__ nbr,             // [N,K]
    const float* __restrict__ resid,         // [N,C] f32 (EPI==1)
    unsigned short* __restrict__ outb,       // bf16 out (EPI==0)
    float* __restrict__ outf)                // f32 out (EPI==1)
{
    const int wid  = threadIdx.x >> 6;
    const int lane = threadIdx.x & 63;
    const int lr   = lane & 15;     // row-in-tile (A) / col-in-tile (B,D)
    const int kg   = lane >> 4;     // k-group 0..3
    const int row  = blockIdx.x * 64 + wid * 16 + lr;   // this lane's A row

    // Preload all 27 neighbor indices -> kills the idx->gather dependent chain.
    int idx[KK];
    {
        const int* np = nbr + (size_t)row * KK;
        #pragma unroll
        for (int k = 0; k < KK; ++k) idx[k] = np[k];
    }

    f32x4 acc[4];
    #pragma unroll
    for (int nt = 0; nt < 4; ++nt) acc[nt] = (f32x4){0.f, 0.f, 0.f, 0.f};

    const unsigned short* xkg = xb + kg * 8;

    // 2-stage pipeline on the A gather.
    short8 na0, na1;
    {
        const unsigned short* p = xkg + (size_t)idx[0] * CH;
        na0 = *reinterpret_cast<const short8*>(p);
        na1 = *reinterpret_cast<const short8*>(p + 32);
    }

    for (int tap = 0; tap < KK; ++tap) {
        short8 a0 = na0, a1 = na1;
        {
            int nx = idx[tap + 1 < KK ? tap + 1 : tap];
            const unsigned short* p = xkg + (size_t)nx * CH;
            na0 = *reinterpret_cast<const short8*>(p);
            na1 = *reinterpret_cast<const short8*>(p + 32);
        }
        const unsigned short* wb = wt + tap * CH * CH + lr * CH + kg * 8;
        #pragma unroll
        for (int nt = 0; nt < 4; ++nt) {
            short8 b0 = *reinterpret_cast<const short8*>(wb + nt * 16 * CH);
            short8 b1 = *reinterpret_cast<const short8*>(wb + nt * 16 * CH + 32);
            acc[nt] = __builtin_amdgcn_mfma_f32_16x16x32_bf16(a0, b0, acc[nt], 0, 0, 0);
            acc[nt] = __builtin_amdgcn_mfma_f32_16x16x32_bf16(a1, b1, acc[nt], 0, 0, 0);
        }
    }

    // Epilogue. D layout: col = lane&15 (within col-tile), row-in-tile = kg*4 + reg.
    const int row0 = blockIdx.x * 64 + wid * 16 + kg * 4;
    #pragma unroll
    for (int nt = 0; nt < 4; ++nt) {
        int col = nt * 16 + lr;
        float bv = bias[col];
        #pragma unroll
        for (int i = 0; i < 4; ++i) {
            float v = acc[nt][i] + bv;
            if (EPI == 0) {
                v = fmaxf(v, 0.f);
                outb[(size_t)(row0 + i) * CH + col] = f2b(v);
            } else {
                v += resid[(size_t)(row0 + i) * CH + col];
                v = fmaxf(v, 0.f);
                outf[(size_t)(row0 + i) * CH + col] = v;
            }
        }
    }
}

extern "C" void kernel_launch(void* const* d_in, const int* in_sizes, int n_in,
                              void* d_out, int out_size, void* d_ws, size_t ws_size,
                              hipStream_t stream) {
    const float* feat = (const float*)d_in[0];
    const float* W1   = (const float*)d_in[1];
    const float* b1   = (const float*)d_in[2];
    const float* W2   = (const float*)d_in[3];
    const float* b2   = (const float*)d_in[4];
    const int*   nbr  = (const int*)d_in[5];
    float* out = (float*)d_out;

    char* ws = (char*)d_ws;
    unsigned short* featb = (unsigned short*)ws;                              // 16.78 MB
    unsigned short* hb    = (unsigned short*)(ws + (size_t)NV * CH * 2);      // 16.78 MB
    unsigned short* wt1   = (unsigned short*)(ws + (size_t)NV * CH * 4);      // 216 KB
    unsigned short* wt2   = wt1 + KK * CH * CH;                               // 216 KB

    prep_feat<<<NV * CH / 4 / 256, 256, 0, stream>>>(feat, featb);
    prep_w<<<2 * KK * CH * CH / 256, 256, 0, stream>>>(W1, W2, wt1, wt2);
    conv_layer<0><<<NV / 64, 256, 0, stream>>>(featb, wt1, b1, nbr, nullptr, hb, nullptr);
    conv_layer<1><<<NV / 64, 256, 0, stream>>>(hb, wt2, b2, nbr, feat, nullptr, out);
}

// Round 3
// 231.362 us; speedup vs baseline: 2.2746x; 2.2746x over previous
//
#include <hip/hip_runtime.h>
#include <stdint.h>

typedef short short8 __attribute__((ext_vector_type(8)));
typedef float f32x4 __attribute__((ext_vector_type(4)));

#define NV 131072
#define KK 27
#define CH 64
#define DD 3   // pipeline depth in taps

__device__ inline unsigned short f2b(float f) {
    unsigned u = __float_as_uint(f);
    u += 0x7fffu + ((u >> 16) & 1u);   // round-to-nearest-even
    return (unsigned short)(u >> 16);
}

// feat f32 [N,C] -> bf16 bits [N,C]
__global__ void prep_feat(const float* __restrict__ feat, unsigned short* __restrict__ featb) {
    int i = blockIdx.x * blockDim.x + threadIdx.x;
    float4 v = reinterpret_cast<const float4*>(feat)[i];
    ushort4 o;
    o.x = f2b(v.x); o.y = f2b(v.y); o.z = f2b(v.z); o.w = f2b(v.w);
    reinterpret_cast<ushort4*>(featb)[i] = o;
}

// W [K][Ci][Co] f32 -> Wt [K][Co][Ci] bf16
__global__ void prep_w(const float* __restrict__ W1, const float* __restrict__ W2,
                       unsigned short* __restrict__ wt1, unsigned short* __restrict__ wt2) {
    int id = blockIdx.x * blockDim.x + threadIdx.x;
    const float* W = W1; unsigned short* wt = wt1;
    int e = id;
    if (e >= KK * CH * CH) { e -= KK * CH * CH; W = W2; wt = wt2; }
    int k = e >> 12, o = (e >> 6) & 63, c = e & 63;
    wt[e] = f2b(W[k * CH * CH + c * CH + o]);
}

__device__ inline void gld16(const void* gsrc, void* ldst) {
    __builtin_amdgcn_global_load_lds(
        (const __attribute__((address_space(1))) unsigned int*)gsrc,
        (__attribute__((address_space(3))) unsigned int*)ldst,
        16, 0, 0);
}

// Block = 256 thr = 4 waves; wave owns 16 rows x 64 cols; grid = N/64 = 2048.
// LDS ring: DD stages x 16 KB:
//   A: per-wave 2 KB at s*16384 + wid*2048, layout [chunk c=ch/8][row r][16B]
//   B: shared 8 KB at   s*16384 + 8192,     layout [chunk c][o][16B]
// Per wave per tap: 2 A-gather + 2 B global_load_lds instrs (1 KB each).
template <int EPI>
__global__ __launch_bounds__(256, 4) void conv_layer(
    const unsigned short* __restrict__ xb,   // [N,C] bf16 input
    const unsigned short* __restrict__ wt,   // [K,Co,Ci] bf16 transposed weights
    const float* __restrict__ bias,          // [C]
    const int* __restrict__ nbr,             // [N,K]
    const float* __restrict__ resid,         // [N,C] f32 (EPI==1)
    unsigned short* __restrict__ outb,       // bf16 out (EPI==0)
    float* __restrict__ outf)                // f32 out (EPI==1)
{
    __shared__ char lds[DD * 16384];
    const int wid  = threadIdx.x >> 6;
    const int lane = threadIdx.x & 63;
    const int lr   = lane & 15;
    const int kg   = lane >> 4;
    const int rowbase = blockIdx.x * 64 + wid * 16;

    // per-lane: idx[k] = neighbor of row (rowbase+lr) at tap k (27 VGPRs, static)
    int idx[KK];
    {
        const int* np = nbr + (size_t)(rowbase + lr) * KK;
        #pragma unroll
        for (int k = 0; k < KK; ++k) idx[k] = np[k];
    }

    f32x4 acc[4];
    #pragma unroll
    for (int nt = 0; nt < 4; ++nt) acc[nt] = (f32x4){0.f, 0.f, 0.f, 0.f};

    // stage tap t into slot t%DD (t must be compile-time constant under unroll)
    auto stage = [&](int t) {
        char* sb = lds + (t % DD) * 16384;
        // A: instr i covers chunks i*4..i*4+3; lane l -> (c = i*4 + (l>>4), r = l&15)
        char* ab = sb + wid * 2048;
        const unsigned short* ga = xb + (size_t)idx[t] * CH;
        gld16(ga + (0 * 4 + kg) * 8, ab);
        gld16(ga + (1 * 4 + kg) * 8, ab + 1024);
        // B: wave handles chunk-planes j = wid*2, wid*2+1; lane l -> (c = j, o = l)
        const unsigned short* gw = wt + t * CH * CH;
        char* bb = sb + 8192;
        int j0 = wid * 2, j1 = wid * 2 + 1;
        gld16(gw + (size_t)lane * CH + j0 * 8, bb + j0 * 1024);
        gld16(gw + (size_t)lane * CH + j1 * 8, bb + j1 * 1024);
        asm volatile("" ::: "memory");   // keep tap-groups ordered in the vmcnt queue
    };

    stage(0); stage(1); stage(2);

    #pragma unroll
    for (int t = 0; t < KK; ++t) {
        // wait for this tap's 4 staging instrs (counted, never drain the ring)
        if (t <= 24)      asm volatile("s_waitcnt vmcnt(8)" ::: "memory");
        else if (t == 25) asm volatile("s_waitcnt vmcnt(4)" ::: "memory");
        else              asm volatile("s_waitcnt vmcnt(0)" ::: "memory");
        __builtin_amdgcn_s_barrier();

        const char* sb = lds + (t % DD) * 16384;
        const char* ab = sb + wid * 2048;
        short8 a0 = *reinterpret_cast<const short8*>(ab + kg * 256 + lr * 16);
        short8 a1 = *reinterpret_cast<const short8*>(ab + (kg + 4) * 256 + lr * 16);
        const char* bb = sb + 8192;
        short8 b0[4], b1[4];
        #pragma unroll
        for (int nt = 0; nt < 4; ++nt) {
            b0[nt] = *reinterpret_cast<const short8*>(bb + kg * 1024 + (nt * 16 + lr) * 16);
            b1[nt] = *reinterpret_cast<const short8*>(bb + (kg + 4) * 1024 + (nt * 16 + lr) * 16);
        }
        // reads must be complete before anyone overwrites this slot
        asm volatile("s_waitcnt lgkmcnt(0)" ::: "memory");
        __builtin_amdgcn_s_barrier();

        if (t + DD < KK) stage(t + DD);

        #pragma unroll
        for (int nt = 0; nt < 4; ++nt) {
            acc[nt] = __builtin_amdgcn_mfma_f32_16x16x32_bf16(a0, b0[nt], acc[nt], 0, 0, 0);
            acc[nt] = __builtin_amdgcn_mfma_f32_16x16x32_bf16(a1, b1[nt], acc[nt], 0, 0, 0);
        }
    }

    // Epilogue. D layout: col = nt*16 + lr, row-in-tile = kg*4 + i.
    const int row0 = rowbase + kg * 4;
    #pragma unroll
    for (int nt = 0; nt < 4; ++nt) {
        int col = nt * 16 + lr;
        float bv = bias[col];
        #pragma unroll
        for (int i = 0; i < 4; ++i) {
            float v = acc[nt][i] + bv;
            if (EPI == 0) {
                v = fmaxf(v, 0.f);
                outb[(size_t)(row0 + i) * CH + col] = f2b(v);
            } else {
                v += resid[(size_t)(row0 + i) * CH + col];
                v = fmaxf(v, 0.f);
                outf[(size_t)(row0 + i) * CH + col] = v;
            }
        }
    }
}

extern "C" void kernel_launch(void* const* d_in, const int* in_sizes, int n_in,
                              void* d_out, int out_size, void* d_ws, size_t ws_size,
                              hipStream_t stream) {
    const float* feat = (const float*)d_in[0];
    const float* W1   = (const float*)d_in[1];
    const float* b1   = (const float*)d_in[2];
    const float* W2   = (const float*)d_in[3];
    const float* b2   = (const float*)d_in[4];
    const int*   nbr  = (const int*)d_in[5];
    float* out = (float*)d_out;

    char* ws = (char*)d_ws;
    unsigned short* featb = (unsigned short*)ws;                              // 16.78 MB
    unsigned short* hb    = (unsigned short*)(ws + (size_t)NV * CH * 2);      // 16.78 MB
    unsigned short* wt1   = (unsigned short*)(ws + (size_t)NV * CH * 4);      // 216 KB
    unsigned short* wt2   = wt1 + KK * CH * CH;                               // 216 KB

    prep_feat<<<NV * CH / 4 / 256, 256, 0, stream>>>(feat, featb);
    prep_w<<<2 * KK * CH * CH / 256, 256, 0, stream>>>(W1, W2, wt1, wt2);
    conv_layer<0><<<NV / 64, 256, 0, stream>>>(featb, wt1, b1, nbr, nullptr, hb, nullptr);
    conv_layer<1><<<NV / 64, 256, 0, stream>>>(hb, wt2, b2, nbr, feat, nullptr, out);
}